// Round 1
// baseline (686.391 us; speedup 1.0000x reference)
//
#include <hip/hip_runtime.h>
#include <hip/hip_bf16.h>

#define BB   8
#define SS   512
#define DD   128
#define HH   512
#define NBK  32
#define BSR  4096          // B*S rows

// ---------------- K1: embedding gather + positional (pe indexed by batch) ----
__global__ void k_embed(const int* __restrict__ idx, const float* __restrict__ emb,
                        const float* __restrict__ pe, float* __restrict__ x) {
    int t = blockIdx.x * 256 + threadIdx.x;        // over BSR*DD = 524288
    int tok = t >> 7, d = t & 127;
    int b = tok >> 9;
    x[t] = emb[(size_t)idx[tok] * DD + d] + pe[b * DD + d];
}

// ---------------- K2: q = x@Wq+bq / v = x@Wv+bv  (blockIdx.y selects) --------
__global__ __launch_bounds__(128) void k_qv(const float* __restrict__ x,
        const float* __restrict__ Wq, const float* __restrict__ bq,
        const float* __restrict__ Wv, const float* __restrict__ bv,
        float* __restrict__ q, float* __restrict__ v) {
    int rb = blockIdx.x;                           // 0..127, 32 rows each
    const float* W    = blockIdx.y ? Wv : Wq;
    const float* bias = blockIdx.y ? bv : bq;
    float* out        = blockIdx.y ? v  : q;
    __shared__ __align__(16) float xs[32][128];
    int tid = threadIdx.x;                         // 128 threads
    #pragma unroll
    for (int j = 0; j < 32; ++j)
        xs[j][tid] = x[(size_t)(rb * 32 + j) * DD + tid];
    __syncthreads();
    int col = tid;
    float acc[32];
    #pragma unroll
    for (int r = 0; r < 32; ++r) acc[r] = 0.f;
    for (int k4 = 0; k4 < 32; ++k4) {
        float w0 = W[(k4 * 4 + 0) * DD + col];
        float w1 = W[(k4 * 4 + 1) * DD + col];
        float w2 = W[(k4 * 4 + 2) * DD + col];
        float w3 = W[(k4 * 4 + 3) * DD + col];
        #pragma unroll
        for (int r = 0; r < 32; ++r) {
            float4 xv = *(const float4*)&xs[r][k4 * 4];
            acc[r] += xv.x * w0 + xv.y * w1 + xv.z * w2 + xv.w * w3;
        }
    }
    float bi = bias[col];
    #pragma unroll
    for (int r = 0; r < 32; ++r)
        out[(size_t)(rb * 32 + r) * DD + col] = acc[r] + bi;
}

// ---------------- K3: LSH bucket ids + per-bucket V sums ---------------------
__global__ __launch_bounds__(64) void k_bucket(const float* __restrict__ q,
        const float* __restrict__ v, const float* __restrict__ hyp,
        int* __restrict__ bucket, int* __restrict__ cnt, float* __restrict__ Vb) {
    int tok = blockIdx.x;
    int b = tok >> 9;
    int lane = threadIdx.x;                        // 64 threads
    float q0 = q[(size_t)tok * DD + lane];
    float q1 = q[(size_t)tok * DD + 64 + lane];
    float p0 = q0 * hyp[lane * 5 + 0] + q1 * hyp[(lane + 64) * 5 + 0];
    float p1 = q0 * hyp[lane * 5 + 1] + q1 * hyp[(lane + 64) * 5 + 1];
    float p2 = q0 * hyp[lane * 5 + 2] + q1 * hyp[(lane + 64) * 5 + 2];
    float p3 = q0 * hyp[lane * 5 + 3] + q1 * hyp[(lane + 64) * 5 + 3];
    float p4 = q0 * hyp[lane * 5 + 4] + q1 * hyp[(lane + 64) * 5 + 4];
    #pragma unroll
    for (int o = 1; o < 64; o <<= 1) {
        p0 += __shfl_xor(p0, o, 64);
        p1 += __shfl_xor(p1, o, 64);
        p2 += __shfl_xor(p2, o, 64);
        p3 += __shfl_xor(p3, o, 64);
        p4 += __shfl_xor(p4, o, 64);
    }
    int bk = 0;
    if (p0 + hyp[128 * 5 + 0] >= 0.f) bk |= 1;
    if (p1 + hyp[128 * 5 + 1] >= 0.f) bk |= 2;
    if (p2 + hyp[128 * 5 + 2] >= 0.f) bk |= 4;
    if (p3 + hyp[128 * 5 + 3] >= 0.f) bk |= 8;
    if (p4 + hyp[128 * 5 + 4] >= 0.f) bk |= 16;
    if (lane == 0) {
        bucket[tok] = bk;
        atomicAdd(&cnt[(b << 5) + bk], 1);
    }
    float v0 = v[(size_t)tok * DD + lane];
    float v1 = v[(size_t)tok * DD + 64 + lane];
    atomicAdd(&Vb[(size_t)((b << 5) + bk) * DD + lane], v0);
    atomicAdd(&Vb[(size_t)((b << 5) + bk) * DD + 64 + lane], v1);
}

// ---------------- K3b: Vsum[b][d] = sum_i Vb[b][i][d] ------------------------
__global__ void k_vsum(const float* __restrict__ Vb, float* __restrict__ Vsum) {
    int b = blockIdx.x, d = threadIdx.x;           // 8 x 128
    float s = 0.f;
    #pragma unroll
    for (int i = 0; i < NBK; ++i) s += Vb[(size_t)((b << 5) + i) * DD + d];
    Vsum[b * DD + d] = s;
}

// ---------------- K4a: G = scale * q qT per batch, + row max (>=0) -----------
__global__ __launch_bounds__(256) void k_gram(const float* __restrict__ q,
        float* __restrict__ G, float* __restrict__ M) {
    int b = blockIdx.z, st = blockIdx.y, tt = blockIdx.x;   // 64x64 tile
    const float* qb = q + (size_t)b * SS * DD;
    __shared__ __align__(16) float AsT[64][68];
    __shared__ __align__(16) float BsT[64][68];
    __shared__ int rmax[64];
    int tid = threadIdx.x;
    int tx = tid & 15, ty = tid >> 4;
    if (tid < 64) rmax[tid] = 0;
    float acc[4][4];
    #pragma unroll
    for (int i = 0; i < 4; ++i)
        #pragma unroll
        for (int j = 0; j < 4; ++j) acc[i][j] = 0.f;
    int ks = tid >> 2;           // 0..63 (k within chunk)
    int rs0 = tid & 3;
    for (int kc = 0; kc < DD; kc += 64) {
        __syncthreads();
        #pragma unroll
        for (int j = 0; j < 16; ++j) {
            int i = rs0 + 4 * j;
            AsT[ks][i] = qb[(size_t)(st * 64 + i) * DD + kc + ks];
            BsT[ks][i] = qb[(size_t)(tt * 64 + i) * DD + kc + ks];
        }
        __syncthreads();
        #pragma unroll 4
        for (int k = 0; k < 64; ++k) {
            float4 a4 = *(const float4*)&AsT[k][ty * 4];
            float4 b4 = *(const float4*)&BsT[k][tx * 4];
            acc[0][0] += a4.x * b4.x; acc[0][1] += a4.x * b4.y; acc[0][2] += a4.x * b4.z; acc[0][3] += a4.x * b4.w;
            acc[1][0] += a4.y * b4.x; acc[1][1] += a4.y * b4.y; acc[1][2] += a4.y * b4.z; acc[1][3] += a4.y * b4.w;
            acc[2][0] += a4.z * b4.x; acc[2][1] += a4.z * b4.y; acc[2][2] += a4.z * b4.z; acc[2][3] += a4.z * b4.w;
            acc[3][0] += a4.w * b4.x; acc[3][1] += a4.w * b4.y; acc[3][2] += a4.w * b4.z; acc[3][3] += a4.w * b4.w;
        }
    }
    const float scale = 0.088388347648318447f;     // 1/sqrt(128)
    #pragma unroll
    for (int ii = 0; ii < 4; ++ii) {
        float4 g4;
        g4.x = acc[ii][0] * scale; g4.y = acc[ii][1] * scale;
        g4.z = acc[ii][2] * scale; g4.w = acc[ii][3] * scale;
        int srow = st * 64 + ty * 4 + ii;
        *(float4*)&G[((size_t)(b * SS + srow)) * SS + tt * 64 + tx * 4] = g4;
        float rm = fmaxf(fmaxf(g4.x, g4.y), fmaxf(g4.z, g4.w));
        rm = fmaxf(rm, 0.f);
        atomicMax(&rmax[ty * 4 + ii], __float_as_int(rm));   // non-neg: int cmp valid
    }
    __syncthreads();
    if (tid < 64) atomicMax((int*)&M[b * SS + st * 64 + tid], rmax[tid]);
}

// ---------------- K4b: e = exp(G - M); W_j, Z, r_i, R per row ----------------
__global__ __launch_bounds__(256) void k_stats(float* __restrict__ e,
        const float* __restrict__ M, const int* __restrict__ bucket,
        const int* __restrict__ cnt, float* __restrict__ rstat) {
    int row = blockIdx.x;                          // 0..4095
    int b = row >> 9;
    int tid = threadIdx.x;
    __shared__ float Wsh[NBK];
    __shared__ float rsh[NBK];
    __shared__ float Zsh;
    if (tid < NBK) Wsh[tid] = 0.f;
    __syncthreads();
    float Ms = M[row];
    float* erow = e + (size_t)row * SS;
    #pragma unroll
    for (int j = 0; j < 2; ++j) {
        int t = tid + 256 * j;
        float ev = __expf(erow[t] - Ms);
        erow[t] = ev;
        atomicAdd(&Wsh[bucket[(b << 9) + t]], ev);
    }
    __syncthreads();
    if (tid == 0) {
        float z = 0.f;
        #pragma unroll
        for (int i = 0; i < NBK; ++i) z += Wsh[i];
        Zsh = z;
    }
    __syncthreads();
    int bs = bucket[row];
    if (tid < NBK) {
        float enM = __expf(-Ms);
        float r = 1.0f / (Zsh - Wsh[tid] + (float)cnt[(b << 5) + tid] * enM);
        rstat[(size_t)row * 33 + tid] = r;
        rsh[tid] = (tid == bs) ? 0.f : r;
    }
    __syncthreads();
    if (tid == 0) {
        float R = 0.f;
        #pragma unroll
        for (int i = 0; i < NBK; ++i) R += rsh[i];
        rstat[(size_t)row * 33 + 32] = R;
    }
}

// ---------------- K5: acc[s] = sum_t e*(R - r_{bt})*v[t] + uniform -----------
__global__ __launch_bounds__(256) void k_attn(const float* __restrict__ e,
        const float* __restrict__ v, const float* __restrict__ rstat,
        const int* __restrict__ bucket, const float* __restrict__ Vb,
        const float* __restrict__ Vsum, float* __restrict__ out) {
    int b = blockIdx.y, s0 = blockIdx.x * 32;
    int tid = threadIdx.x, tx = tid & 31, ty = tid >> 5;
    __shared__ __align__(16) float vt[32][128];
    __shared__ float cs[32][33];
    __shared__ float rs[32][32];
    __shared__ float Rb[32];
    __shared__ int bsr[32];
    __shared__ int bkt[32];
    #pragma unroll
    for (int j = 0; j < 4; ++j) {
        int idx = tid + 256 * j;                   // 1024 = 32x32
        int s = idx >> 5, i = idx & 31;
        rs[s][i] = rstat[(size_t)(b * SS + s0 + s) * 33 + i];
    }
    if (tid < 32) {
        Rb[tid]  = rstat[(size_t)(b * SS + s0 + tid) * 33 + 32];
        bsr[tid] = bucket[b * SS + s0 + tid];
    }
    float4 acc[4];
    #pragma unroll
    for (int r = 0; r < 4; ++r) acc[r] = make_float4(0.f, 0.f, 0.f, 0.f);
    for (int tt = 0; tt < 16; ++tt) {
        __syncthreads();
        #pragma unroll
        for (int j = 0; j < 16; ++j) {
            int idx = tid + 256 * j;
            int t = idx >> 7, d = idx & 127;
            vt[t][d] = v[(size_t)(b * SS + tt * 32 + t) * DD + d];
        }
        if (tid < 32) bkt[tid] = bucket[b * SS + tt * 32 + tid];
        __syncthreads();
        #pragma unroll
        for (int j = 0; j < 4; ++j) {
            int idx = tid + 256 * j;
            int s = idx >> 5, t = idx & 31;
            int bt = bkt[t];
            float ev = e[(size_t)(b * SS + s0 + s) * SS + tt * 32 + t];
            float rsel = (bt == bsr[s]) ? 0.f : rs[s][bt];
            cs[s][t] = ev * (Rb[s] - rsel);
        }
        __syncthreads();
        #pragma unroll 8
        for (int t = 0; t < 32; ++t) {
            float4 v4 = *(const float4*)&vt[t][tx * 4];
            #pragma unroll
            for (int rr = 0; rr < 4; ++rr) {
                float c = cs[ty * 4 + rr][t];
                acc[rr].x += c * v4.x; acc[rr].y += c * v4.y;
                acc[rr].z += c * v4.z; acc[rr].w += c * v4.w;
            }
        }
    }
    const float inv512 = 1.0f / 512.0f;
    float4 vs = *(const float4*)&Vsum[b * DD + tx * 4];
    #pragma unroll
    for (int rr = 0; rr < 4; ++rr) {
        int sl = ty * 4 + rr;
        int bs = bsr[sl];
        float4 vb = *(const float4*)&Vb[(size_t)((b << 5) + bs) * DD + tx * 4];
        float4 r;
        r.x = acc[rr].x + (vs.x - vb.x) * inv512;
        r.y = acc[rr].y + (vs.y - vb.y) * inv512;
        r.z = acc[rr].z + (vs.z - vb.z) * inv512;
        r.w = acc[rr].w + (vs.w - vb.w) * inv512;
        *(float4*)&out[(size_t)(b * SS + s0 + sl) * DD + tx * 4] = r;
    }
}

// ---------------- K6: LayerNorm over D=128 -----------------------------------
__global__ __launch_bounds__(256) void k_ln(const float* __restrict__ in,
        const float* __restrict__ g, const float* __restrict__ bb,
        float* __restrict__ out) {
    int row = blockIdx.x * 4 + (threadIdx.x >> 6);
    int lane = threadIdx.x & 63;
    const float* p = in + (size_t)row * DD;
    float x0 = p[lane], x1 = p[lane + 64];
    float s = x0 + x1;
    #pragma unroll
    for (int o = 1; o < 64; o <<= 1) s += __shfl_xor(s, o, 64);
    float mean = s * (1.f / 128.f);
    float d0 = x0 - mean, d1 = x1 - mean;
    float vsum = d0 * d0 + d1 * d1;
    #pragma unroll
    for (int o = 1; o < 64; o <<= 1) vsum += __shfl_xor(vsum, o, 64);
    float rstd = rsqrtf(vsum * (1.f / 128.f) + 1e-5f);
    out[(size_t)row * DD + lane]      = d0 * rstd * g[lane] + bb[lane];
    out[(size_t)row * DD + 64 + lane] = d1 * rstd * g[lane + 64] + bb[lane + 64];
}

// ---------------- K7a: h = relu(x@W1 + b1) -----------------------------------
__global__ __launch_bounds__(256) void k_ffn1(const float* __restrict__ x,
        const float* __restrict__ W1, const float* __restrict__ b1,
        float* __restrict__ h) {
    int cb = blockIdx.x;                           // 0..3 col blocks of 128
    int rb = blockIdx.y;                           // 0..127 row blocks of 32
    __shared__ __align__(16) float xs[32][128];
    int tid = threadIdx.x;
    #pragma unroll
    for (int j = 0; j < 16; ++j) {
        int idx = tid + 256 * j;
        int r = idx >> 7, k = idx & 127;
        xs[r][k] = x[(size_t)(rb * 32 + r) * DD + k];
    }
    __syncthreads();
    int col = cb * 128 + (tid & 127);
    int rg = (tid >> 7) * 16;
    float acc[16];
    #pragma unroll
    for (int r = 0; r < 16; ++r) acc[r] = 0.f;
    for (int k4 = 0; k4 < 32; ++k4) {
        float w0 = W1[(size_t)(k4 * 4 + 0) * HH + col];
        float w1 = W1[(size_t)(k4 * 4 + 1) * HH + col];
        float w2 = W1[(size_t)(k4 * 4 + 2) * HH + col];
        float w3 = W1[(size_t)(k4 * 4 + 3) * HH + col];
        #pragma unroll
        for (int r = 0; r < 16; ++r) {
            float4 xv = *(const float4*)&xs[rg + r][k4 * 4];
            acc[r] += xv.x * w0 + xv.y * w1 + xv.z * w2 + xv.w * w3;
        }
    }
    float bias = b1[col];
    #pragma unroll
    for (int r = 0; r < 16; ++r)
        h[(size_t)(rb * 32 + rg + r) * HH + col] = fmaxf(acc[r] + bias, 0.f);
}

// ---------------- K7b: y = h@W2 + b2 + x (residual) --------------------------
__global__ __launch_bounds__(256) void k_ffn2(const float* __restrict__ h,
        const float* __restrict__ W2, const float* __restrict__ b2,
        const float* __restrict__ xres, float* __restrict__ y) {
    int rb = blockIdx.x;                           // 0..255 row blocks of 16
    __shared__ __align__(16) float hs[16][128];
    int tid = threadIdx.x;
    int col = tid & 127;
    int rg = (tid >> 7) * 8;
    float acc[8];
    #pragma unroll
    for (int r = 0; r < 8; ++r) acc[r] = 0.f;
    for (int kc = 0; kc < 4; ++kc) {
        __syncthreads();
        #pragma unroll
        for (int j = 0; j < 8; ++j) {
            int idx = tid + 256 * j;
            int r = idx >> 7, k = idx & 127;
            hs[r][k] = h[(size_t)(rb * 16 + r) * HH + kc * 128 + k];
        }
        __syncthreads();
        for (int k4 = 0; k4 < 32; ++k4) {
            int kbase = kc * 128 + k4 * 4;
            float w0 = W2[(size_t)(kbase + 0) * DD + col];
            float w1 = W2[(size_t)(kbase + 1) * DD + col];
            float w2 = W2[(size_t)(kbase + 2) * DD + col];
            float w3 = W2[(size_t)(kbase + 3) * DD + col];
            #pragma unroll
            for (int r = 0; r < 8; ++r) {
                float4 hv = *(const float4*)&hs[rg + r][k4 * 4];
                acc[r] += hv.x * w0 + hv.y * w1 + hv.z * w2 + hv.w * w3;
            }
        }
    }
    float bias = b2[col];
    #pragma unroll
    for (int r = 0; r < 8; ++r) {
        int row = rb * 16 + rg + r;
        y[(size_t)row * DD + col] = acc[r] + bias + xres[(size_t)row * DD + col];
    }
}

// ---------------- K9: out = x_flat @ Wm + bm ---------------------------------
__global__ __launch_bounds__(256) void k_final(const float* __restrict__ x,
        const float* __restrict__ Wm, const float* __restrict__ bm,
        float* __restrict__ out) {
    int b = blockIdx.x / 6, o = blockIdx.x % 6;
    int tid = threadIdx.x;
    const float* xr = x + (size_t)b * 65536;
    float p = 0.f;
    for (int j = tid; j < 65536; j += 256) p += xr[j] * Wm[(size_t)j * 6 + o];
    __shared__ float red[256];
    red[tid] = p;
    __syncthreads();
    #pragma unroll
    for (int st = 128; st; st >>= 1) {
        if (tid < st) red[tid] += red[tid + st];
        __syncthreads();
    }
    if (tid == 0) out[b * 6 + o] = red[0] + bm[o];
}

// ---------------- orchestration ----------------------------------------------
extern "C" void kernel_launch(void* const* d_in, const int* in_sizes, int n_in,
                              void* d_out, int out_size, void* d_ws, size_t ws_size,
                              hipStream_t stream) {
    const int*   inputs = (const int*)  d_in[0];
    const float* emb    = (const float*)d_in[1];
    const float* pe     = (const float*)d_in[2];
    const float* hyp    = (const float*)d_in[3];
    const float* Wq     = (const float*)d_in[4];
    const float* bq     = (const float*)d_in[5];
    const float* Wv     = (const float*)d_in[6];
    const float* bv     = (const float*)d_in[7];
    const float* ln_g   = (const float*)d_in[8];
    const float* ln_b   = (const float*)d_in[9];
    const float* W1     = (const float*)d_in[10];
    const float* b1     = (const float*)d_in[11];
    const float* W2     = (const float*)d_in[12];
    const float* b2     = (const float*)d_in[13];
    const float* Wm     = (const float*)d_in[14];
    const float* bm     = (const float*)d_in[15];

    float* F = (float*)d_ws;
    float* x     = F + 0;         // 524288
    float* q     = F + 524288;    // 524288
    float* v     = F + 1048576;   // 524288
    float* e     = F + 1572864;   // 2097152  (G -> e; reused as h)
    float* a     = F + 3670016;   // 524288   (attn out; reused as y)
    float* Vb    = F + 4194304;   // 32768
    float* Vsum  = F + 4227072;   // 1024
    float* M     = F + 4228096;   // 4096
    int*   cnt   = (int*)(F + 4232192);   // 256 ints
    float* rstat = F + 4232448;   // 135168 (8*512*33)
    int*   bucket= (int*)(F + 4367616);   // 4096 ints
    // total ~17.5 MB

    k_embed<<<2048, 256, 0, stream>>>(inputs, emb, pe, x);

    for (int enc = 0; enc < 2; ++enc) {
        // zero Vb, Vsum, M, cnt (contiguous region)
        hipMemsetAsync(Vb, 0, (size_t)(32768 + 1024 + 4096 + 256) * 4, stream);
        k_qv<<<dim3(128, 2), 128, 0, stream>>>(x, Wq, bq, Wv, bv, q, v);
        k_bucket<<<4096, 64, 0, stream>>>(q, v, hyp, bucket, cnt, Vb);
        k_vsum<<<8, 128, 0, stream>>>(Vb, Vsum);
        k_gram<<<dim3(8, 8, 8), 256, 0, stream>>>(q, e, M);
        k_stats<<<4096, 256, 0, stream>>>(e, M, bucket, cnt, rstat);
        k_attn<<<dim3(16, 8), 256, 0, stream>>>(e, v, rstat, bucket, Vb, Vsum, a);
        k_ln<<<1024, 256, 0, stream>>>(a, ln_g, ln_b, x);
        k_ffn1<<<dim3(4, 128), 256, 0, stream>>>(x, W1, b1, e /*h*/);
        k_ffn2<<<256, 256, 0, stream>>>(e /*h*/, W2, b2, x, a /*y*/);
        k_ln<<<1024, 256, 0, stream>>>(a, ln_g, ln_b, x);
    }
    k_final<<<48, 256, 0, stream>>>(x, Wm, bm, (float*)d_out);
}

// Round 2
// 423.783 us; speedup vs baseline: 1.6197x; 1.6197x over previous
//
#include <hip/hip_runtime.h>
#include <hip/hip_bf16.h>

#define BB   8
#define SS   512
#define DD   128
#define HH   512
#define NBK  32

// ---------------- K1: embedding gather + positional (pe indexed by batch) ----
__global__ void k_embed(const int* __restrict__ idx, const float* __restrict__ emb,
                        const float* __restrict__ pe, float* __restrict__ x) {
    int t = blockIdx.x * 256 + threadIdx.x;        // over 4096*128 = 524288
    int tok = t >> 7, d = t & 127;
    int b = tok >> 9;
    x[t] = emb[(size_t)idx[tok] * DD + d] + pe[b * DD + d];
}

// ---------------- K2: q|v = x@W + b, both in one block -----------------------
__global__ __launch_bounds__(256) void k_qv(const float* __restrict__ x,
        const float* __restrict__ Wq, const float* __restrict__ bq,
        const float* __restrict__ Wv, const float* __restrict__ bv,
        float* __restrict__ q, float* __restrict__ v) {
    int rb = blockIdx.x;                           // 0..255, 16 rows each
    __shared__ __align__(16) float xs[16][128];
    int tid = threadIdx.x;
    #pragma unroll
    for (int j = 0; j < 8; ++j) {
        int lin = tid + 256 * j;
        int r = lin >> 7, k = lin & 127;
        xs[r][k] = x[(size_t)(rb * 16 + r) * DD + k];
    }
    __syncthreads();
    int which = tid >> 7, col = tid & 127;
    const float* W    = which ? Wv : Wq;
    const float* bias = which ? bv : bq;
    float* out        = which ? v  : q;
    float acc[16];
    #pragma unroll
    for (int r = 0; r < 16; ++r) acc[r] = 0.f;
    for (int k4 = 0; k4 < 32; ++k4) {
        float w0 = W[(k4 * 4 + 0) * DD + col];
        float w1 = W[(k4 * 4 + 1) * DD + col];
        float w2 = W[(k4 * 4 + 2) * DD + col];
        float w3 = W[(k4 * 4 + 3) * DD + col];
        #pragma unroll
        for (int r = 0; r < 16; ++r) {
            float4 xv = *(const float4*)&xs[r][k4 * 4];
            acc[r] += xv.x * w0 + xv.y * w1 + xv.z * w2 + xv.w * w3;
        }
    }
    float bi = bias[col];
    #pragma unroll
    for (int r = 0; r < 16; ++r)
        out[(size_t)(rb * 16 + r) * DD + col] = acc[r] + bi;
}

// ---------------- K3: LSH bucket ids + per-bucket V sums ---------------------
__global__ __launch_bounds__(64) void k_bucket(const float* __restrict__ q,
        const float* __restrict__ v, const float* __restrict__ hyp,
        int* __restrict__ bucket, int* __restrict__ cnt, float* __restrict__ Vb) {
    int tok = blockIdx.x;
    int b = tok >> 9;
    int lane = threadIdx.x;                        // 64 threads
    float q0 = q[(size_t)tok * DD + lane];
    float q1 = q[(size_t)tok * DD + 64 + lane];
    float p0 = q0 * hyp[lane * 5 + 0] + q1 * hyp[(lane + 64) * 5 + 0];
    float p1 = q0 * hyp[lane * 5 + 1] + q1 * hyp[(lane + 64) * 5 + 1];
    float p2 = q0 * hyp[lane * 5 + 2] + q1 * hyp[(lane + 64) * 5 + 2];
    float p3 = q0 * hyp[lane * 5 + 3] + q1 * hyp[(lane + 64) * 5 + 3];
    float p4 = q0 * hyp[lane * 5 + 4] + q1 * hyp[(lane + 64) * 5 + 4];
    #pragma unroll
    for (int o = 1; o < 64; o <<= 1) {
        p0 += __shfl_xor(p0, o, 64);
        p1 += __shfl_xor(p1, o, 64);
        p2 += __shfl_xor(p2, o, 64);
        p3 += __shfl_xor(p3, o, 64);
        p4 += __shfl_xor(p4, o, 64);
    }
    int bk = 0;
    if (p0 + hyp[128 * 5 + 0] >= 0.f) bk |= 1;
    if (p1 + hyp[128 * 5 + 1] >= 0.f) bk |= 2;
    if (p2 + hyp[128 * 5 + 2] >= 0.f) bk |= 4;
    if (p3 + hyp[128 * 5 + 3] >= 0.f) bk |= 8;
    if (p4 + hyp[128 * 5 + 4] >= 0.f) bk |= 16;
    if (lane == 0) {
        bucket[tok] = bk;
        atomicAdd(&cnt[(b << 5) + bk], 1);
    }
    float v0 = v[(size_t)tok * DD + lane];
    float v1 = v[(size_t)tok * DD + 64 + lane];
    atomicAdd(&Vb[(size_t)((b << 5) + bk) * DD + lane], v0);
    atomicAdd(&Vb[(size_t)((b << 5) + bk) * DD + 64 + lane], v1);
}

// ---------------- K3b: Vsum[b][d] = sum_i Vb[b][i][d] ------------------------
__global__ void k_vsum(const float* __restrict__ Vb, float* __restrict__ Vsum) {
    int b = blockIdx.x, d = threadIdx.x;           // 8 x 128
    float s = 0.f;
    #pragma unroll
    for (int i = 0; i < NBK; ++i) s += Vb[(size_t)((b << 5) + i) * DD + d];
    Vsum[b * DD + d] = s;
}

// ---------------- K4a: G = scale * q qT per batch, + row max (>=0) -----------
__global__ __launch_bounds__(256) void k_gram(const float* __restrict__ q,
        float* __restrict__ G, float* __restrict__ M) {
    int b = blockIdx.z, st = blockIdx.y, tt = blockIdx.x;   // 64x64 tile
    const float* qb = q + (size_t)b * SS * DD;
    __shared__ __align__(16) float AsT[64][68];
    __shared__ __align__(16) float BsT[64][68];
    __shared__ int rmax[64];
    int tid = threadIdx.x;
    int tx = tid & 15, ty = tid >> 4;
    if (tid < 64) rmax[tid] = 0;
    float acc[4][4];
    #pragma unroll
    for (int i = 0; i < 4; ++i)
        #pragma unroll
        for (int j = 0; j < 4; ++j) acc[i][j] = 0.f;
    int ks = tid >> 2;
    int rs0 = tid & 3;
    for (int kc = 0; kc < DD; kc += 64) {
        __syncthreads();
        #pragma unroll
        for (int j = 0; j < 16; ++j) {
            int i = rs0 + 4 * j;
            AsT[ks][i] = qb[(size_t)(st * 64 + i) * DD + kc + ks];
            BsT[ks][i] = qb[(size_t)(tt * 64 + i) * DD + kc + ks];
        }
        __syncthreads();
        #pragma unroll 4
        for (int k = 0; k < 64; ++k) {
            float4 a4 = *(const float4*)&AsT[k][ty * 4];
            float4 b4 = *(const float4*)&BsT[k][tx * 4];
            acc[0][0] += a4.x * b4.x; acc[0][1] += a4.x * b4.y; acc[0][2] += a4.x * b4.z; acc[0][3] += a4.x * b4.w;
            acc[1][0] += a4.y * b4.x; acc[1][1] += a4.y * b4.y; acc[1][2] += a4.y * b4.z; acc[1][3] += a4.y * b4.w;
            acc[2][0] += a4.z * b4.x; acc[2][1] += a4.z * b4.y; acc[2][2] += a4.z * b4.z; acc[2][3] += a4.z * b4.w;
            acc[3][0] += a4.w * b4.x; acc[3][1] += a4.w * b4.y; acc[3][2] += a4.w * b4.z; acc[3][3] += a4.w * b4.w;
        }
    }
    const float scale = 0.088388347648318447f;
    #pragma unroll
    for (int ii = 0; ii < 4; ++ii) {
        float4 g4;
        g4.x = acc[ii][0] * scale; g4.y = acc[ii][1] * scale;
        g4.z = acc[ii][2] * scale; g4.w = acc[ii][3] * scale;
        int srow = st * 64 + ty * 4 + ii;
        *(float4*)&G[((size_t)(b * SS + srow)) * SS + tt * 64 + tx * 4] = g4;
        float rm = fmaxf(fmaxf(g4.x, g4.y), fmaxf(g4.z, g4.w));
        rm = fmaxf(rm, 0.f);
        atomicMax(&rmax[ty * 4 + ii], __float_as_int(rm));
    }
    __syncthreads();
    if (tid < 64) atomicMax((int*)&M[b * SS + st * 64 + tid], rmax[tid]);
}

// ---------------- K4b: e -> c = e*(R - r_{b_t}) folded per row ---------------
__global__ __launch_bounds__(256) void k_stats(float* __restrict__ e,
        const float* __restrict__ M, const int* __restrict__ bucket,
        const int* __restrict__ cnt) {
    int row = blockIdx.x;                          // 0..4095
    int b = row >> 9;
    int tid = threadIdx.x;
    __shared__ float Wsh[NBK];
    __shared__ float rsh[NBK];
    __shared__ float Rsh;
    if (tid < NBK) Wsh[tid] = 0.f;
    __syncthreads();
    float Ms = M[row];
    float* erow = e + (size_t)row * SS;
    float ev0 = __expf(erow[tid] - Ms);
    float ev1 = __expf(erow[tid + 256] - Ms);
    int bk0 = bucket[(b << 9) + tid];
    int bk1 = bucket[(b << 9) + tid + 256];
    atomicAdd(&Wsh[bk0], ev0);
    atomicAdd(&Wsh[bk1], ev1);
    __syncthreads();
    if (tid < NBK) {
        float z = 0.f;
        #pragma unroll
        for (int i = 0; i < NBK; ++i) z += Wsh[i];
        float enM = __expf(-Ms);
        rsh[tid] = 1.0f / (z - Wsh[tid] + (float)cnt[(b << 5) + tid] * enM);
    }
    __syncthreads();
    int bs = bucket[row];
    if (tid == 0) {
        float R = 0.f;
        #pragma unroll
        for (int i = 0; i < NBK; ++i) R += (i == bs) ? 0.f : rsh[i];
        Rsh = R;
    }
    __syncthreads();
    float R = Rsh;
    erow[tid]       = ev0 * (R - ((bk0 == bs) ? 0.f : rsh[bk0]));
    erow[tid + 256] = ev1 * (R - ((bk1 == bs) ? 0.f : rsh[bk1]));
}

// ---------------- K5: out = C @ V + uniform, fused LayerNorm -> x ------------
__global__ __launch_bounds__(256) void k_attn(const float* __restrict__ c,
        const float* __restrict__ v, const int* __restrict__ bucket,
        const float* __restrict__ Vb, const float* __restrict__ Vsum,
        const float* __restrict__ g, const float* __restrict__ lb,
        float* __restrict__ x) {
    int b = blockIdx.y, s0 = blockIdx.x * 8;       // 8 rows per block
    int tid = threadIdx.x;
    int col = tid & 127, rbase = (tid >> 7) * 4;   // 4 rows per thread
    __shared__ __align__(16) float vt[32][128];    // 16 KB
    __shared__ float csm[8][33];
    __shared__ __align__(16) float osh[8][132];
    float acc[4] = {0.f, 0.f, 0.f, 0.f};
    for (int kc = 0; kc < SS; kc += 32) {
        __syncthreads();
        #pragma unroll
        for (int j = 0; j < 4; ++j) {
            int idx4 = tid + 256 * j;              // 0..1023
            int t = idx4 >> 5, d4 = (idx4 & 31) * 4;
            *(float4*)&vt[t][d4] = *(const float4*)&v[(size_t)(b * SS + kc + t) * DD + d4];
        }
        {
            int s = tid >> 5, t = tid & 31;
            csm[s][t] = c[(size_t)(b * SS + s0 + s) * SS + kc + t];
        }
        __syncthreads();
        #pragma unroll 8
        for (int t = 0; t < 32; ++t) {
            float vv = vt[t][col];
            #pragma unroll
            for (int r = 0; r < 4; ++r)
                acc[r] += csm[rbase + r][t] * vv;
        }
    }
    const float inv512 = 1.0f / 512.0f;
    float vs = Vsum[b * DD + col];
    #pragma unroll
    for (int r = 0; r < 4; ++r) {
        int row = rbase + r;
        int bs = bucket[b * SS + s0 + row];
        float vbv = Vb[(size_t)((b << 5) + bs) * DD + col];
        osh[row][col] = acc[r] + (vs - vbv) * inv512;
    }
    __syncthreads();
    // LayerNorm: 32 threads per row, 4 values each
    int row = tid >> 5, l = tid & 31;
    float4 val = *(const float4*)&osh[row][l * 4];
    float s = val.x + val.y + val.z + val.w;
    float ss = val.x * val.x + val.y * val.y + val.z * val.z + val.w * val.w;
    #pragma unroll
    for (int o = 1; o < 32; o <<= 1) {
        s  += __shfl_xor(s, o, 32);
        ss += __shfl_xor(ss, o, 32);
    }
    float mean = s * (1.f / 128.f);
    float var = ss * (1.f / 128.f) - mean * mean;
    float rstd = rsqrtf(var + 1e-5f);
    float4 gv = *(const float4*)&g[l * 4];
    float4 bv = *(const float4*)&lb[l * 4];
    float4 out;
    out.x = (val.x - mean) * rstd * gv.x + bv.x;
    out.y = (val.y - mean) * rstd * gv.y + bv.y;
    out.z = (val.z - mean) * rstd * gv.z + bv.z;
    out.w = (val.w - mean) * rstd * gv.w + bv.w;
    *(float4*)&x[(size_t)(b * SS + s0 + row) * DD + l * 4] = out;
}

// ---------------- K7a: h = relu(x@W1 + b1) -----------------------------------
__global__ __launch_bounds__(256) void k_ffn1(const float* __restrict__ x,
        const float* __restrict__ W1, const float* __restrict__ b1,
        float* __restrict__ h) {
    int cb = blockIdx.x;                           // 0..3 col blocks of 128
    int rb = blockIdx.y;                           // 0..127 row blocks of 32
    __shared__ __align__(16) float xs[32][128];
    int tid = threadIdx.x;
    #pragma unroll
    for (int j = 0; j < 16; ++j) {
        int idx = tid + 256 * j;
        int r = idx >> 7, k = idx & 127;
        xs[r][k] = x[(size_t)(rb * 32 + r) * DD + k];
    }
    __syncthreads();
    int col = cb * 128 + (tid & 127);
    int rg = (tid >> 7) * 16;
    float acc[16];
    #pragma unroll
    for (int r = 0; r < 16; ++r) acc[r] = 0.f;
    for (int k4 = 0; k4 < 32; ++k4) {
        float w0 = W1[(size_t)(k4 * 4 + 0) * HH + col];
        float w1 = W1[(size_t)(k4 * 4 + 1) * HH + col];
        float w2 = W1[(size_t)(k4 * 4 + 2) * HH + col];
        float w3 = W1[(size_t)(k4 * 4 + 3) * HH + col];
        #pragma unroll
        for (int r = 0; r < 16; ++r) {
            float4 xv = *(const float4*)&xs[rg + r][k4 * 4];
            acc[r] += xv.x * w0 + xv.y * w1 + xv.z * w2 + xv.w * w3;
        }
    }
    float bias = b1[col];
    #pragma unroll
    for (int r = 0; r < 16; ++r)
        h[(size_t)(rb * 32 + rg + r) * HH + col] = fmaxf(acc[r] + bias, 0.f);
}

// ---------------- K7b: y = h@W2 + b2 + x, fused LayerNorm -> x ---------------
__global__ __launch_bounds__(256) void k_ffn2(const float* __restrict__ h,
        const float* __restrict__ W2, const float* __restrict__ b2,
        const float* __restrict__ g, const float* __restrict__ lb,
        float* __restrict__ x) {
    int rb = blockIdx.x;                           // 0..255 row blocks of 16
    __shared__ __align__(16) float hs[16][128];
    __shared__ __align__(16) float osh[16][132];
    int tid = threadIdx.x;
    int col = tid & 127;
    int rg = (tid >> 7) * 8;
    float acc[8];
    #pragma unroll
    for (int r = 0; r < 8; ++r) acc[r] = 0.f;
    for (int kc = 0; kc < 4; ++kc) {
        __syncthreads();
        #pragma unroll
        for (int j = 0; j < 8; ++j) {
            int idx = tid + 256 * j;
            int r = idx >> 7, k = idx & 127;
            hs[r][k] = h[(size_t)(rb * 16 + r) * HH + kc * 128 + k];
        }
        __syncthreads();
        for (int k4 = 0; k4 < 32; ++k4) {
            int kbase = kc * 128 + k4 * 4;
            float w0 = W2[(size_t)(kbase + 0) * DD + col];
            float w1 = W2[(size_t)(kbase + 1) * DD + col];
            float w2 = W2[(size_t)(kbase + 2) * DD + col];
            float w3 = W2[(size_t)(kbase + 3) * DD + col];
            #pragma unroll
            for (int r = 0; r < 8; ++r) {
                float4 hv = *(const float4*)&hs[rg + r][k4 * 4];
                acc[r] += hv.x * w0 + hv.y * w1 + hv.z * w2 + hv.w * w3;
            }
        }
    }
    float bias = b2[col];
    #pragma unroll
    for (int r = 0; r < 8; ++r) {
        int row = rb * 16 + rg + r;
        osh[rg + r][col] = acc[r] + bias + x[(size_t)row * DD + col];
    }
    __syncthreads();
    // LayerNorm: 16 threads per row, 8 values each
    int row = tid >> 4, l = tid & 15;
    float4 v0 = *(const float4*)&osh[row][l * 8];
    float4 v1 = *(const float4*)&osh[row][l * 8 + 4];
    float s  = v0.x + v0.y + v0.z + v0.w + v1.x + v1.y + v1.z + v1.w;
    float ss = v0.x*v0.x + v0.y*v0.y + v0.z*v0.z + v0.w*v0.w
             + v1.x*v1.x + v1.y*v1.y + v1.z*v1.z + v1.w*v1.w;
    #pragma unroll
    for (int o = 1; o < 16; o <<= 1) {
        s  += __shfl_xor(s, o, 16);
        ss += __shfl_xor(ss, o, 16);
    }
    float mean = s * (1.f / 128.f);
    float var = ss * (1.f / 128.f) - mean * mean;
    float rstd = rsqrtf(var + 1e-5f);
    float4 g0 = *(const float4*)&g[l * 8];
    float4 g1 = *(const float4*)&g[l * 8 + 4];
    float4 b0 = *(const float4*)&lb[l * 8];
    float4 b1v = *(const float4*)&lb[l * 8 + 4];
    float4 o0, o1;
    o0.x = (v0.x - mean) * rstd * g0.x + b0.x;
    o0.y = (v0.y - mean) * rstd * g0.y + b0.y;
    o0.z = (v0.z - mean) * rstd * g0.z + b0.z;
    o0.w = (v0.w - mean) * rstd * g0.w + b0.w;
    o1.x = (v1.x - mean) * rstd * g1.x + b1v.x;
    o1.y = (v1.y - mean) * rstd * g1.y + b1v.y;
    o1.z = (v1.z - mean) * rstd * g1.z + b1v.z;
    o1.w = (v1.w - mean) * rstd * g1.w + b1v.w;
    size_t base = (size_t)(rb * 16 + row) * DD + l * 8;
    *(float4*)&x[base]     = o0;
    *(float4*)&x[base + 4] = o1;
}

// ---------------- K9: out = x_flat @ Wm + bm (split-K + atomics) -------------
__global__ __launch_bounds__(256) void k_final(const float* __restrict__ x,
        const float* __restrict__ Wm, const float* __restrict__ bm,
        float* __restrict__ out) {
    int b = blockIdx.x >> 5, chunk = blockIdx.x & 31;   // 2048 elems per chunk
    int tid = threadIdx.x;
    const float* xr = x + (size_t)b * 65536 + chunk * 2048;
    const float* wr = Wm + (size_t)(chunk * 2048) * 6;
    float p[6] = {0.f, 0.f, 0.f, 0.f, 0.f, 0.f};
    #pragma unroll
    for (int it = 0; it < 8; ++it) {
        int j = tid + 256 * it;
        float xv = xr[j];
        const float* w = wr + (size_t)j * 6;
        p[0] += xv * w[0]; p[1] += xv * w[1]; p[2] += xv * w[2];
        p[3] += xv * w[3]; p[4] += xv * w[4]; p[5] += xv * w[5];
    }
    #pragma unroll
    for (int o = 0; o < 6; ++o)
        #pragma unroll
        for (int off = 1; off < 64; off <<= 1)
            p[o] += __shfl_xor(p[o], off, 64);
    __shared__ float red[4][6];
    int wv = tid >> 6;
    if ((tid & 63) == 0)
        #pragma unroll
        for (int o = 0; o < 6; ++o) red[wv][o] = p[o];
    __syncthreads();
    if (tid < 6) {
        float sv = red[0][tid] + red[1][tid] + red[2][tid] + red[3][tid];
        if (chunk == 0) sv += bm[tid];
        atomicAdd(&out[b * 6 + tid], sv);
    }
}

// ---------------- orchestration ----------------------------------------------
extern "C" void kernel_launch(void* const* d_in, const int* in_sizes, int n_in,
                              void* d_out, int out_size, void* d_ws, size_t ws_size,
                              hipStream_t stream) {
    const int*   inputs = (const int*)  d_in[0];
    const float* emb    = (const float*)d_in[1];
    const float* pe     = (const float*)d_in[2];
    const float* hyp    = (const float*)d_in[3];
    const float* Wq     = (const float*)d_in[4];
    const float* bq     = (const float*)d_in[5];
    const float* Wv     = (const float*)d_in[6];
    const float* bv     = (const float*)d_in[7];
    const float* ln_g   = (const float*)d_in[8];
    const float* ln_b   = (const float*)d_in[9];
    const float* W1     = (const float*)d_in[10];
    const float* b1     = (const float*)d_in[11];
    const float* W2     = (const float*)d_in[12];
    const float* b2     = (const float*)d_in[13];
    const float* Wm     = (const float*)d_in[14];
    const float* bm     = (const float*)d_in[15];

    float* F = (float*)d_ws;
    float* x     = F + 0;         // 524288
    float* q     = F + 524288;    // 524288
    float* v     = F + 1048576;   // 524288
    float* e     = F + 1572864;   // 2097152  (G -> c; reused as h)
    float* Vb    = F + 3670016;   // 32768
    float* Vsum  = F + 3702784;   // 1024
    float* M     = F + 3703808;   // 4096
    int*   cnt   = (int*)(F + 3707904);   // 256 ints
    int*   bucket= (int*)(F + 3708160);   // 4096 ints
    // total ~14.8 MB

    hipMemsetAsync(d_out, 0, (size_t)out_size * 4, stream);
    k_embed<<<2048, 256, 0, stream>>>(inputs, emb, pe, x);

    for (int enc = 0; enc < 2; ++enc) {
        hipMemsetAsync(Vb, 0, (size_t)(32768 + 1024 + 4096 + 256) * 4, stream);
        k_qv<<<256, 256, 0, stream>>>(x, Wq, bq, Wv, bv, q, v);
        k_bucket<<<4096, 64, 0, stream>>>(q, v, hyp, bucket, cnt, Vb);
        k_vsum<<<8, 128, 0, stream>>>(Vb, Vsum);
        k_gram<<<dim3(8, 8, 8), 256, 0, stream>>>(q, e, M);
        k_stats<<<4096, 256, 0, stream>>>(e, M, bucket, cnt);
        k_attn<<<dim3(64, 8), 256, 0, stream>>>(e, v, bucket, Vb, Vsum, ln_g, ln_b, x);
        k_ffn1<<<dim3(4, 128), 256, 0, stream>>>(x, W1, b1, e /*h*/);
        k_ffn2<<<256, 256, 0, stream>>>(e /*h*/, W2, b2, ln_g, ln_b, x);
    }
    k_final<<<48 * 32 / 6, 256, 0, stream>>>(x, Wm, bm, (float*)d_out);
}

// Round 3
// 330.583 us; speedup vs baseline: 2.0763x; 1.2819x over previous
//
#include <hip/hip_runtime.h>
#include <hip/hip_bf16.h>

#define BB   8
#define SS   512
#define DD   128
#define HH   512
#define NBK  32

// ---------------- K1: embedding gather + positional (pe indexed by batch) ----
__global__ void k_embed(const int* __restrict__ idx, const float* __restrict__ emb,
                        const float* __restrict__ pe, float* __restrict__ x) {
    int t = blockIdx.x * 256 + threadIdx.x;        // over 4096*128 = 524288
    int tok = t >> 7, d = t & 127;
    int b = tok >> 9;
    x[t] = emb[(size_t)idx[tok] * DD + d] + pe[b * DD + d];
}

// ---------------- K2: q and v via 4x(2+2) micro, k-packed LDS A --------------
__global__ __launch_bounds__(256) void k_qv(const float* __restrict__ x,
        const float* __restrict__ Wq, const float* __restrict__ bq,
        const float* __restrict__ Wv, const float* __restrict__ bv,
        float* __restrict__ q, float* __restrict__ v) {
    int rb = blockIdx.x;                           // 16 rows per block
    __shared__ __align__(16) float xs[16][132];
    int tid = threadIdx.x;
    #pragma unroll
    for (int it = 0; it < 2; ++it) {
        int lin = tid + 256 * it;                  // 512 float4 slots
        int r = lin >> 5, kq = (lin & 31) * 4;
        *(float4*)&xs[r][kq] = *(const float4*)&x[(size_t)(rb * 16 + r) * DD + kq];
    }
    __syncthreads();
    int tx = tid & 63;                             // col pair: 2tx, 2tx+1
    int ty = tid >> 6;                             // row quad
    float2 aq[4], av[4];
    #pragma unroll
    for (int i = 0; i < 4; ++i) { aq[i] = make_float2(0.f, 0.f); av[i] = make_float2(0.f, 0.f); }
    for (int g = 0; g < 32; ++g) {
        int kb = g * 4;
        float4 a0 = *(const float4*)&xs[ty * 4 + 0][kb];
        float4 a1 = *(const float4*)&xs[ty * 4 + 1][kb];
        float4 a2 = *(const float4*)&xs[ty * 4 + 2][kb];
        float4 a3 = *(const float4*)&xs[ty * 4 + 3][kb];
        #pragma unroll
        for (int j = 0; j < 4; ++j) {
            float2 wq = *(const float2*)&Wq[(size_t)(kb + j) * DD + tx * 2];
            float2 wv = *(const float2*)&Wv[(size_t)(kb + j) * DD + tx * 2];
            float c0 = (j == 0) ? a0.x : (j == 1) ? a0.y : (j == 2) ? a0.z : a0.w;
            float c1 = (j == 0) ? a1.x : (j == 1) ? a1.y : (j == 2) ? a1.z : a1.w;
            float c2 = (j == 0) ? a2.x : (j == 1) ? a2.y : (j == 2) ? a2.z : a2.w;
            float c3 = (j == 0) ? a3.x : (j == 1) ? a3.y : (j == 2) ? a3.z : a3.w;
            aq[0].x += c0 * wq.x; aq[0].y += c0 * wq.y; av[0].x += c0 * wv.x; av[0].y += c0 * wv.y;
            aq[1].x += c1 * wq.x; aq[1].y += c1 * wq.y; av[1].x += c1 * wv.x; av[1].y += c1 * wv.y;
            aq[2].x += c2 * wq.x; aq[2].y += c2 * wq.y; av[2].x += c2 * wv.x; av[2].y += c2 * wv.y;
            aq[3].x += c3 * wq.x; aq[3].y += c3 * wq.y; av[3].x += c3 * wv.x; av[3].y += c3 * wv.y;
        }
    }
    float2 bqv = *(const float2*)&bq[tx * 2];
    float2 bvv = *(const float2*)&bv[tx * 2];
    #pragma unroll
    for (int i = 0; i < 4; ++i) {
        int row = rb * 16 + ty * 4 + i;
        float2 oq = make_float2(aq[i].x + bqv.x, aq[i].y + bqv.y);
        float2 ov = make_float2(av[i].x + bvv.x, av[i].y + bvv.y);
        *(float2*)&q[(size_t)row * DD + tx * 2] = oq;
        *(float2*)&v[(size_t)row * DD + tx * 2] = ov;
    }
}

// ---------------- K3: LSH bucket ids + per-bucket V sums (4 tokens/block) ----
__global__ __launch_bounds__(256) void k_bucket(const float* __restrict__ q,
        const float* __restrict__ v, const float* __restrict__ hyp,
        int* __restrict__ bucket, int* __restrict__ cnt, float* __restrict__ Vb) {
    int tok = blockIdx.x * 4 + (threadIdx.x >> 6);
    int b = tok >> 9;
    int lane = threadIdx.x & 63;
    float q0 = q[(size_t)tok * DD + lane];
    float q1 = q[(size_t)tok * DD + 64 + lane];
    float p0 = q0 * hyp[lane * 5 + 0] + q1 * hyp[(lane + 64) * 5 + 0];
    float p1 = q0 * hyp[lane * 5 + 1] + q1 * hyp[(lane + 64) * 5 + 1];
    float p2 = q0 * hyp[lane * 5 + 2] + q1 * hyp[(lane + 64) * 5 + 2];
    float p3 = q0 * hyp[lane * 5 + 3] + q1 * hyp[(lane + 64) * 5 + 3];
    float p4 = q0 * hyp[lane * 5 + 4] + q1 * hyp[(lane + 64) * 5 + 4];
    #pragma unroll
    for (int o = 1; o < 64; o <<= 1) {
        p0 += __shfl_xor(p0, o, 64);
        p1 += __shfl_xor(p1, o, 64);
        p2 += __shfl_xor(p2, o, 64);
        p3 += __shfl_xor(p3, o, 64);
        p4 += __shfl_xor(p4, o, 64);
    }
    int bk = 0;
    if (p0 + hyp[128 * 5 + 0] >= 0.f) bk |= 1;
    if (p1 + hyp[128 * 5 + 1] >= 0.f) bk |= 2;
    if (p2 + hyp[128 * 5 + 2] >= 0.f) bk |= 4;
    if (p3 + hyp[128 * 5 + 3] >= 0.f) bk |= 8;
    if (p4 + hyp[128 * 5 + 4] >= 0.f) bk |= 16;
    if (lane == 0) {
        bucket[tok] = bk;
        atomicAdd(&cnt[(b << 5) + bk], 1);
    }
    float v0 = v[(size_t)tok * DD + lane];
    float v1 = v[(size_t)tok * DD + 64 + lane];
    atomicAdd(&Vb[(size_t)((b << 5) + bk) * DD + lane], v0);
    atomicAdd(&Vb[(size_t)((b << 5) + bk) * DD + 64 + lane], v1);
}

// ---------------- K3b: Vsum[b][d] = sum_i Vb[b][i][d] ------------------------
__global__ void k_vsum(const float* __restrict__ Vb, float* __restrict__ Vsum) {
    int b = blockIdx.x, d = threadIdx.x;
    float s = 0.f;
    #pragma unroll
    for (int i = 0; i < NBK; ++i) s += Vb[(size_t)((b << 5) + i) * DD + d];
    Vsum[b * DD + d] = s;
}

// ---------------- K4a: G = scale * q qT per batch, + row max (>=0) -----------
__global__ __launch_bounds__(256) void k_gram(const float* __restrict__ q,
        float* __restrict__ G, float* __restrict__ M) {
    int b = blockIdx.z, st = blockIdx.y, tt = blockIdx.x;   // 64x64 tile
    const float* qb = q + (size_t)b * SS * DD;
    __shared__ __align__(16) float AsT[64][68];
    __shared__ __align__(16) float BsT[64][68];
    __shared__ int rmax[64];
    int tid = threadIdx.x;
    int tx = tid & 15, ty = tid >> 4;
    if (tid < 64) rmax[tid] = 0;
    float acc[4][4];
    #pragma unroll
    for (int i = 0; i < 4; ++i)
        #pragma unroll
        for (int j = 0; j < 4; ++j) acc[i][j] = 0.f;
    int ks = tid >> 2;
    int rs0 = tid & 3;
    for (int kc = 0; kc < DD; kc += 64) {
        __syncthreads();
        #pragma unroll
        for (int j = 0; j < 16; ++j) {
            int i = rs0 + 4 * j;
            AsT[ks][i] = qb[(size_t)(st * 64 + i) * DD + kc + ks];
            BsT[ks][i] = qb[(size_t)(tt * 64 + i) * DD + kc + ks];
        }
        __syncthreads();
        #pragma unroll 4
        for (int k = 0; k < 64; ++k) {
            float4 a4 = *(const float4*)&AsT[k][ty * 4];
            float4 b4 = *(const float4*)&BsT[k][tx * 4];
            acc[0][0] += a4.x * b4.x; acc[0][1] += a4.x * b4.y; acc[0][2] += a4.x * b4.z; acc[0][3] += a4.x * b4.w;
            acc[1][0] += a4.y * b4.x; acc[1][1] += a4.y * b4.y; acc[1][2] += a4.y * b4.z; acc[1][3] += a4.y * b4.w;
            acc[2][0] += a4.z * b4.x; acc[2][1] += a4.z * b4.y; acc[2][2] += a4.z * b4.z; acc[2][3] += a4.z * b4.w;
            acc[3][0] += a4.w * b4.x; acc[3][1] += a4.w * b4.y; acc[3][2] += a4.w * b4.z; acc[3][3] += a4.w * b4.w;
        }
    }
    const float scale = 0.088388347648318447f;
    #pragma unroll
    for (int ii = 0; ii < 4; ++ii) {
        float4 g4;
        g4.x = acc[ii][0] * scale; g4.y = acc[ii][1] * scale;
        g4.z = acc[ii][2] * scale; g4.w = acc[ii][3] * scale;
        int srow = st * 64 + ty * 4 + ii;
        *(float4*)&G[((size_t)(b * SS + srow)) * SS + tt * 64 + tx * 4] = g4;
        float rm = fmaxf(fmaxf(g4.x, g4.y), fmaxf(g4.z, g4.w));
        rm = fmaxf(rm, 0.f);
        atomicMax(&rmax[ty * 4 + ii], __float_as_int(rm));
    }
    __syncthreads();
    if (tid < 64) atomicMax((int*)&M[b * SS + st * 64 + tid], rmax[tid]);
}

// ---------------- K4b: e -> c = e*(R - r_{b_t}) folded per row ---------------
__global__ __launch_bounds__(256) void k_stats(float* __restrict__ e,
        const float* __restrict__ M, const int* __restrict__ bucket,
        const int* __restrict__ cnt) {
    int row = blockIdx.x;                          // 0..4095
    int b = row >> 9;
    int tid = threadIdx.x;
    __shared__ float Wsh[NBK];
    __shared__ float rsh[NBK];
    __shared__ float Rsh;
    if (tid < NBK) Wsh[tid] = 0.f;
    __syncthreads();
    float Ms = M[row];
    float* erow = e + (size_t)row * SS;
    float ev0 = __expf(erow[tid] - Ms);
    float ev1 = __expf(erow[tid + 256] - Ms);
    int bk0 = bucket[(b << 9) + tid];
    int bk1 = bucket[(b << 9) + tid + 256];
    atomicAdd(&Wsh[bk0], ev0);
    atomicAdd(&Wsh[bk1], ev1);
    __syncthreads();
    if (tid < NBK) {
        float z = 0.f;
        #pragma unroll
        for (int i = 0; i < NBK; ++i) z += Wsh[i];
        float enM = __expf(-Ms);
        rsh[tid] = 1.0f / (z - Wsh[tid] + (float)cnt[(b << 5) + tid] * enM);
    }
    __syncthreads();
    int bs = bucket[row];
    if (tid == 0) {
        float R = 0.f;
        #pragma unroll
        for (int i = 0; i < NBK; ++i) R += (i == bs) ? 0.f : rsh[i];
        Rsh = R;
    }
    __syncthreads();
    float R = Rsh;
    erow[tid]       = ev0 * (R - ((bk0 == bs) ? 0.f : rsh[bk0]));
    erow[tid + 256] = ev1 * (R - ((bk1 == bs) ? 0.f : rsh[bk1]));
}

// ---------------- K5: out = C@V + uniform, fused LN.  micro 4x4, split-K2 ----
__global__ __launch_bounds__(256) void k_attn(const float* __restrict__ c,
        const float* __restrict__ v, const int* __restrict__ bucket,
        const float* __restrict__ Vb, const float* __restrict__ Vsum,
        const float* __restrict__ g, const float* __restrict__ lb,
        float* __restrict__ x) {
    int b = blockIdx.y, s0 = blockIdx.x * 16;      // 16 rows per block
    int tid = threadIdx.x;
    __shared__ __align__(16) float cs[16][520];    // k-packed A operand, 33 KB
    __shared__ __align__(16) float osh[16][132];
    // stage c rows (coalesced b128)
    {
        int row = tid >> 4;
        int k0 = (tid & 15) * 4;
        const float* crow = c + (size_t)(b * SS + s0 + row) * SS;
        #pragma unroll
        for (int it = 0; it < 8; ++it)
            *(float4*)&cs[row][k0 + it * 64] = *(const float4*)&crow[k0 + it * 64];
    }
    __syncthreads();
    int kh = tid >> 7;                             // 0..1 : k half
    int ty = (tid >> 5) & 3;                       // row quad
    int tx = tid & 31;                             // col quad
    float4 acc[4];
    #pragma unroll
    for (int i = 0; i < 4; ++i) acc[i] = make_float4(0.f, 0.f, 0.f, 0.f);
    const float* vb_base = v + (size_t)b * SS * DD + tx * 4;
    for (int gg = 0; gg < 64; ++gg) {
        int kb = kh * 256 + gg * 4;
        float4 a0 = *(const float4*)&cs[ty * 4 + 0][kb];
        float4 a1 = *(const float4*)&cs[ty * 4 + 1][kb];
        float4 a2 = *(const float4*)&cs[ty * 4 + 2][kb];
        float4 a3 = *(const float4*)&cs[ty * 4 + 3][kb];
        #pragma unroll
        for (int j = 0; j < 4; ++j) {
            float4 vj = *(const float4*)&vb_base[(size_t)(kb + j) * DD];
            float c0 = (j == 0) ? a0.x : (j == 1) ? a0.y : (j == 2) ? a0.z : a0.w;
            float c1 = (j == 0) ? a1.x : (j == 1) ? a1.y : (j == 2) ? a1.z : a1.w;
            float c2 = (j == 0) ? a2.x : (j == 1) ? a2.y : (j == 2) ? a2.z : a2.w;
            float c3 = (j == 0) ? a3.x : (j == 1) ? a3.y : (j == 2) ? a3.z : a3.w;
            acc[0].x += c0 * vj.x; acc[0].y += c0 * vj.y; acc[0].z += c0 * vj.z; acc[0].w += c0 * vj.w;
            acc[1].x += c1 * vj.x; acc[1].y += c1 * vj.y; acc[1].z += c1 * vj.z; acc[1].w += c1 * vj.w;
            acc[2].x += c2 * vj.x; acc[2].y += c2 * vj.y; acc[2].z += c2 * vj.z; acc[2].w += c2 * vj.w;
            acc[3].x += c3 * vj.x; acc[3].y += c3 * vj.y; acc[3].z += c3 * vj.z; acc[3].w += c3 * vj.w;
        }
    }
    // kh=1 writes partials, kh=0 adds + uniform term
    if (kh == 1) {
        #pragma unroll
        for (int i = 0; i < 4; ++i)
            *(float4*)&osh[ty * 4 + i][tx * 4] = acc[i];
    }
    __syncthreads();
    if (kh == 0) {
        const float inv512 = 1.0f / 512.0f;
        float4 vs = *(const float4*)&Vsum[b * DD + tx * 4];
        #pragma unroll
        for (int i = 0; i < 4; ++i) {
            int row = ty * 4 + i;
            int bs = bucket[b * SS + s0 + row];
            float4 vb4 = *(const float4*)&Vb[(size_t)((b << 5) + bs) * DD + tx * 4];
            float4 p = *(const float4*)&osh[row][tx * 4];
            p.x += acc[i].x + (vs.x - vb4.x) * inv512;
            p.y += acc[i].y + (vs.y - vb4.y) * inv512;
            p.z += acc[i].z + (vs.z - vb4.z) * inv512;
            p.w += acc[i].w + (vs.w - vb4.w) * inv512;
            *(float4*)&osh[row][tx * 4] = p;
        }
    }
    __syncthreads();
    // LayerNorm: 16 rows x 16 lanes, 8 floats each
    int row = tid >> 4, l = tid & 15;
    float4 v0 = *(const float4*)&osh[row][l * 8];
    float4 v1 = *(const float4*)&osh[row][l * 8 + 4];
    float s  = v0.x + v0.y + v0.z + v0.w + v1.x + v1.y + v1.z + v1.w;
    float ss = v0.x*v0.x + v0.y*v0.y + v0.z*v0.z + v0.w*v0.w
             + v1.x*v1.x + v1.y*v1.y + v1.z*v1.z + v1.w*v1.w;
    #pragma unroll
    for (int o = 1; o < 16; o <<= 1) {
        s  += __shfl_xor(s, o, 16);
        ss += __shfl_xor(ss, o, 16);
    }
    float mean = s * (1.f / 128.f);
    float var = ss * (1.f / 128.f) - mean * mean;
    float rstd = rsqrtf(var + 1e-5f);
    float4 g0 = *(const float4*)&g[l * 8];
    float4 g1 = *(const float4*)&g[l * 8 + 4];
    float4 b0 = *(const float4*)&lb[l * 8];
    float4 b1v = *(const float4*)&lb[l * 8 + 4];
    float4 o0, o1;
    o0.x = (v0.x - mean) * rstd * g0.x + b0.x;
    o0.y = (v0.y - mean) * rstd * g0.y + b0.y;
    o0.z = (v0.z - mean) * rstd * g0.z + b0.z;
    o0.w = (v0.w - mean) * rstd * g0.w + b0.w;
    o1.x = (v1.x - mean) * rstd * g1.x + b1v.x;
    o1.y = (v1.y - mean) * rstd * g1.y + b1v.y;
    o1.z = (v1.z - mean) * rstd * g1.z + b1v.z;
    o1.w = (v1.w - mean) * rstd * g1.w + b1v.w;
    size_t base = (size_t)(b * SS + s0 + row) * DD + l * 8;
    *(float4*)&x[base]     = o0;
    *(float4*)&x[base + 4] = o1;
}

// ---------------- K7: fused FFN: relu(x@W1+b1)@W2+b2 + x, then LN -> x -------
__global__ __launch_bounds__(512) void k_ffn(const float* __restrict__ x,
        const float* __restrict__ W1, const float* __restrict__ b1,
        const float* __restrict__ W2, const float* __restrict__ b2,
        const float* __restrict__ g, const float* __restrict__ lb,
        float* __restrict__ xout) {
    int rb = blockIdx.x;                           // 16 rows per block
    int tid = threadIdx.x;
    __shared__ __align__(16) float xs[16][132];    // 8.4 KB (A + residual)
    __shared__ __align__(16) float hs[16][520];    // 33 KB
    __shared__ __align__(16) float osh[16][132];   // 8.4 KB
    {
        int r = tid >> 5, kq = (tid & 31) * 4;
        *(float4*)&xs[r][kq] = *(const float4*)&x[(size_t)(rb * 16 + r) * DD + kq];
    }
    __syncthreads();
    // Phase B: h = relu(x@W1+b1), micro 4x4, cols via tx (128 quads = 512 cols)
    {
        int tx = tid & 127, ty = tid >> 7;
        float4 acc[4];
        #pragma unroll
        for (int i = 0; i < 4; ++i) acc[i] = make_float4(0.f, 0.f, 0.f, 0.f);
        for (int gg = 0; gg < 32; ++gg) {
            int kb = gg * 4;
            float4 a0 = *(const float4*)&xs[ty * 4 + 0][kb];
            float4 a1 = *(const float4*)&xs[ty * 4 + 1][kb];
            float4 a2 = *(const float4*)&xs[ty * 4 + 2][kb];
            float4 a3 = *(const float4*)&xs[ty * 4 + 3][kb];
            #pragma unroll
            for (int j = 0; j < 4; ++j) {
                float4 w = *(const float4*)&W1[(size_t)(kb + j) * HH + tx * 4];
                float c0 = (j == 0) ? a0.x : (j == 1) ? a0.y : (j == 2) ? a0.z : a0.w;
                float c1 = (j == 0) ? a1.x : (j == 1) ? a1.y : (j == 2) ? a1.z : a1.w;
                float c2 = (j == 0) ? a2.x : (j == 1) ? a2.y : (j == 2) ? a2.z : a2.w;
                float c3 = (j == 0) ? a3.x : (j == 1) ? a3.y : (j == 2) ? a3.z : a3.w;
                acc[0].x += c0 * w.x; acc[0].y += c0 * w.y; acc[0].z += c0 * w.z; acc[0].w += c0 * w.w;
                acc[1].x += c1 * w.x; acc[1].y += c1 * w.y; acc[1].z += c1 * w.z; acc[1].w += c1 * w.w;
                acc[2].x += c2 * w.x; acc[2].y += c2 * w.y; acc[2].z += c2 * w.z; acc[2].w += c2 * w.w;
                acc[3].x += c3 * w.x; acc[3].y += c3 * w.y; acc[3].z += c3 * w.z; acc[3].w += c3 * w.w;
            }
        }
        float4 bi = *(const float4*)&b1[tx * 4];
        #pragma unroll
        for (int i = 0; i < 4; ++i) {
            float4 hv;
            hv.x = fmaxf(acc[i].x + bi.x, 0.f);
            hv.y = fmaxf(acc[i].y + bi.y, 0.f);
            hv.z = fmaxf(acc[i].z + bi.z, 0.f);
            hv.w = fmaxf(acc[i].w + bi.w, 0.f);
            *(float4*)&hs[ty * 4 + i][tx * 4] = hv;
        }
    }
    __syncthreads();
    // Phase C: y = h@W2, micro 4x4, split-K4 (kh = tid>>7)
    {
        int kh = tid >> 7;                         // 0..3
        int ty = (tid >> 5) & 3;                   // row quad
        int tx = tid & 31;                         // col quad
        float4 acc[4];
        #pragma unroll
        for (int i = 0; i < 4; ++i) acc[i] = make_float4(0.f, 0.f, 0.f, 0.f);
        for (int gg = 0; gg < 32; ++gg) {
            int kb = kh * 128 + gg * 4;
            float4 a0 = *(const float4*)&hs[ty * 4 + 0][kb];
            float4 a1 = *(const float4*)&hs[ty * 4 + 1][kb];
            float4 a2 = *(const float4*)&hs[ty * 4 + 2][kb];
            float4 a3 = *(const float4*)&hs[ty * 4 + 3][kb];
            #pragma unroll
            for (int j = 0; j < 4; ++j) {
                float4 w = *(const float4*)&W2[(size_t)(kb + j) * DD + tx * 4];
                float c0 = (j == 0) ? a0.x : (j == 1) ? a0.y : (j == 2) ? a0.z : a0.w;
                float c1 = (j == 0) ? a1.x : (j == 1) ? a1.y : (j == 2) ? a1.z : a1.w;
                float c2 = (j == 0) ? a2.x : (j == 1) ? a2.y : (j == 2) ? a2.z : a2.w;
                float c3 = (j == 0) ? a3.x : (j == 1) ? a3.y : (j == 2) ? a3.z : a3.w;
                acc[0].x += c0 * w.x; acc[0].y += c0 * w.y; acc[0].z += c0 * w.z; acc[0].w += c0 * w.w;
                acc[1].x += c1 * w.x; acc[1].y += c1 * w.y; acc[1].z += c1 * w.z; acc[1].w += c1 * w.w;
                acc[2].x += c2 * w.x; acc[2].y += c2 * w.y; acc[2].z += c2 * w.z; acc[2].w += c2 * w.w;
                acc[3].x += c3 * w.x; acc[3].y += c3 * w.y; acc[3].z += c3 * w.z; acc[3].w += c3 * w.w;
            }
        }
        // reduce kh partials into osh (kh=0 adds bias + residual)
        if (kh == 0) {
            float4 bi = *(const float4*)&b2[tx * 4];
            #pragma unroll
            for (int i = 0; i < 4; ++i) {
                int r = ty * 4 + i;
                float4 res = *(const float4*)&xs[r][tx * 4];
                float4 o;
                o.x = acc[i].x + bi.x + res.x;
                o.y = acc[i].y + bi.y + res.y;
                o.z = acc[i].z + bi.z + res.z;
                o.w = acc[i].w + bi.w + res.w;
                *(float4*)&osh[r][tx * 4] = o;
            }
        }
        __syncthreads();
        #pragma unroll
        for (int p = 1; p < 4; ++p) {
            if (kh == p) {
                #pragma unroll
                for (int i = 0; i < 4; ++i) {
                    int r = ty * 4 + i;
                    float4 o = *(const float4*)&osh[r][tx * 4];
                    o.x += acc[i].x; o.y += acc[i].y; o.z += acc[i].z; o.w += acc[i].w;
                    *(float4*)&osh[r][tx * 4] = o;
                }
            }
            __syncthreads();
        }
    }
    // LayerNorm: 16 rows x 32 lanes, float4 each
    int row = tid >> 5, l = tid & 31;
    float4 val = *(const float4*)&osh[row][l * 4];
    float s = val.x + val.y + val.z + val.w;
    float ss = val.x * val.x + val.y * val.y + val.z * val.z + val.w * val.w;
    #pragma unroll
    for (int o = 1; o < 32; o <<= 1) {
        s  += __shfl_xor(s, o, 32);
        ss += __shfl_xor(ss, o, 32);
    }
    float mean = s * (1.f / 128.f);
    float var = ss * (1.f / 128.f) - mean * mean;
    float rstd = rsqrtf(var + 1e-5f);
    float4 gv = *(const float4*)&g[l * 4];
    float4 bv = *(const float4*)&lb[l * 4];
    float4 out;
    out.x = (val.x - mean) * rstd * gv.x + bv.x;
    out.y = (val.y - mean) * rstd * gv.y + bv.y;
    out.z = (val.z - mean) * rstd * gv.z + bv.z;
    out.w = (val.w - mean) * rstd * gv.w + bv.w;
    *(float4*)&xout[(size_t)(rb * 16 + row) * DD + l * 4] = out;
}

// ---------------- K9: out = x_flat @ Wm + bm (split-K + atomics) -------------
__global__ __launch_bounds__(256) void k_final(const float* __restrict__ x,
        const float* __restrict__ Wm, const float* __restrict__ bm,
        float* __restrict__ out) {
    int b = blockIdx.x >> 5, chunk = blockIdx.x & 31;   // 2048 elems per chunk
    int tid = threadIdx.x;
    const float* xr = x + (size_t)b * 65536 + chunk * 2048;
    const float* wr = Wm + (size_t)(chunk * 2048) * 6;
    float p[6] = {0.f, 0.f, 0.f, 0.f, 0.f, 0.f};
    #pragma unroll
    for (int it = 0; it < 8; ++it) {
        int j = tid + 256 * it;
        float xv = xr[j];
        const float* w = wr + (size_t)j * 6;
        p[0] += xv * w[0]; p[1] += xv * w[1]; p[2] += xv * w[2];
        p[3] += xv * w[3]; p[4] += xv * w[4]; p[5] += xv * w[5];
    }
    #pragma unroll
    for (int o = 0; o < 6; ++o)
        #pragma unroll
        for (int off = 1; off < 64; off <<= 1)
            p[o] += __shfl_xor(p[o], off, 64);
    __shared__ float red[4][6];
    int wv = tid >> 6;
    if ((tid & 63) == 0)
        #pragma unroll
        for (int o = 0; o < 6; ++o) red[wv][o] = p[o];
    __syncthreads();
    if (tid < 6) {
        float sv = red[0][tid] + red[1][tid] + red[2][tid] + red[3][tid];
        if (chunk == 0) sv += bm[tid];
        atomicAdd(&out[b * 6 + tid], sv);
    }
}

// ---------------- orchestration ----------------------------------------------
extern "C" void kernel_launch(void* const* d_in, const int* in_sizes, int n_in,
                              void* d_out, int out_size, void* d_ws, size_t ws_size,
                              hipStream_t stream) {
    const int*   inputs = (const int*)  d_in[0];
    const float* emb    = (const float*)d_in[1];
    const float* pe     = (const float*)d_in[2];
    const float* hyp    = (const float*)d_in[3];
    const float* Wq     = (const float*)d_in[4];
    const float* bq     = (const float*)d_in[5];
    const float* Wv     = (const float*)d_in[6];
    const float* bv     = (const float*)d_in[7];
    const float* ln_g   = (const float*)d_in[8];
    const float* ln_b   = (const float*)d_in[9];
    const float* W1     = (const float*)d_in[10];
    const float* b1     = (const float*)d_in[11];
    const float* W2     = (const float*)d_in[12];
    const float* b2     = (const float*)d_in[13];
    const float* Wm     = (const float*)d_in[14];
    const float* bm     = (const float*)d_in[15];

    float* F = (float*)d_ws;
    float* x     = F + 0;         // 524288
    float* q     = F + 524288;    // 524288
    float* v     = F + 1048576;   // 524288
    float* e     = F + 1572864;   // 2097152  (G -> c)
    float* Vb    = F + 3670016;   // 32768
    float* Vsum  = F + 3702784;   // 1024
    float* M     = F + 3703808;   // 4096
    int*   cnt   = (int*)(F + 3707904);   // 256 ints
    int*   bucket= (int*)(F + 3708160);   // 4096 ints

    hipMemsetAsync(d_out, 0, (size_t)out_size * 4, stream);
    k_embed<<<2048, 256, 0, stream>>>(inputs, emb, pe, x);

    for (int enc = 0; enc < 2; ++enc) {
        hipMemsetAsync(Vb, 0, (size_t)(32768 + 1024 + 4096 + 256) * 4, stream);
        k_qv<<<256, 256, 0, stream>>>(x, Wq, bq, Wv, bv, q, v);
        k_bucket<<<1024, 256, 0, stream>>>(q, v, hyp, bucket, cnt, Vb);
        k_vsum<<<8, 128, 0, stream>>>(Vb, Vsum);
        k_gram<<<dim3(8, 8, 8), 256, 0, stream>>>(q, e, M);
        k_stats<<<4096, 256, 0, stream>>>(e, M, bucket, cnt);
        k_attn<<<dim3(32, 8), 256, 0, stream>>>(e, v, bucket, Vb, Vsum, ln_g, ln_b, x);
        k_ffn<<<256, 512, 0, stream>>>(x, W1, b1, W2, b2, ln_g, ln_b, x);
    }
    k_final<<<48 * 32 / 6, 256, 0, stream>>>(x, Wm, bm, (float*)d_out);
}